// Round 1
// baseline (1239.468 us; speedup 1.0000x reference)
//
#include <hip/hip_runtime.h>

typedef unsigned short ushort_t;
typedef short bf16x8 __attribute__((ext_vector_type(8)));
typedef float f32x4 __attribute__((ext_vector_type(4)));

#define H 1900
#define FH 7600      // 4*H
#define BATCH 8192
#define KP 1952      // padded K stride: 1900 m | 20 pad | 10 inputs | 22 pad (mult of 32)
#define NP_A 1920    // padded N for gemmA (m columns)
#define NB 7680      // padded row count of whxT
#define BK 32
#define KITERS (KP / BK)   // 61
static_assert(KITERS % 2 == 1, "tail handling assumes odd KITERS");

// ---- ws layout (bytes) ----
static const size_t OFF_SWX  = 0;          // 7600 f32
static const size_t OFF_SWH  = 32768;      // 7600 f32
static const size_t OFF_SWMX = 65536;      // 1900 f32
static const size_t OFF_SWMH = 73728;      // 1900 f32
static const size_t OFF_WMXN = 81920;      // 10*1920 f32 (pre-scaled wmx_n)
static const size_t OFF_PART = 163840;     // partial colsums: 8*(7600+7600+1900+1900) f32
static const size_t OFF_HBF  = 786432;                   // h_prev bf16 [8192][1952]
static const size_t OFF_MEXT = OFF_HBF + 31981568;       // m_ext bf16 [8192][1952]
static const size_t OFF_WMHT = OFF_MEXT + 31981568;      // wmh_n^T bf16 [1920][1952]
static const size_t OFF_WHXT = OFF_WMHT + 7495680;       // [wh_n|wx_n]^T perm bf16 [7680][1952]
// end = OFF_WHXT + 29982720 ≈ 97.5 MB

// partial-sum sub-offsets (in floats, within OFF_PART)
#define PW_X  0
#define PW_H  60800
#define PW_MX 121600
#define PW_MH 136800

__device__ __forceinline__ ushort_t f2bf(float x) {
  unsigned u = __float_as_uint(x);
  return (ushort_t)((u + 0x7fffu + ((u >> 16) & 1u)) >> 16);
}

// async global->LDS, 16 B per lane; LDS dest = base + lane*16 (wave-uniform base)
__device__ __forceinline__ void gl_lds16(const ushort_t* g, ushort_t* lds) {
  __builtin_amdgcn_global_load_lds(
      (const __attribute__((address_space(1))) unsigned int*)(g),
      (__attribute__((address_space(3))) unsigned int*)(lds), 16, 0, 0);
}

// ---------------- scales: per-column l2-norm partials, then gain*rsqrt ----------------
__global__ void colsum_partial_kernel(const float* __restrict__ wx, const float* __restrict__ wh,
                                      const float* __restrict__ wmx, const float* __restrict__ wmh,
                                      float* __restrict__ parts) {
  int c = blockIdx.x * 256 + threadIdx.x;
  int y = blockIdx.y, p = blockIdx.z;
  const float* W; int K, N; float* out;
  if (y == 0)      { W = wx;  K = 10;   N = FH; out = parts + PW_X  + (size_t)p * FH; }
  else if (y == 1) { W = wh;  K = 1900; N = FH; out = parts + PW_H  + (size_t)p * FH; }
  else if (y == 2) { W = wmx; K = 10;   N = H;  out = parts + PW_MX + (size_t)p * H;  }
  else             { W = wmh; K = 1900; N = H;  out = parts + PW_MH + (size_t)p * H;  }
  if (c >= N) return;
  int rp = (K + 7) / 8;
  int r0 = p * rp, r1 = r0 + rp; if (r1 > K) r1 = K;
  float s = 0.f;
  for (int r = r0; r < r1; ++r) { float v = W[(size_t)r * N + c]; s += v * v; }
  out[c] = s;
}

__global__ void scales_final_kernel(const float* __restrict__ parts,
                                    const float* __restrict__ gx, const float* __restrict__ gh,
                                    const float* __restrict__ gmx, const float* __restrict__ gmh,
                                    float* __restrict__ s_wx, float* __restrict__ s_wh,
                                    float* __restrict__ s_wmx, float* __restrict__ s_wmh) {
  int c = blockIdx.x * 256 + threadIdx.x;
  int y = blockIdx.y;
  const float* pp; int N; const float* g; float* out;
  if (y == 0)      { pp = parts + PW_X;  N = FH; g = gx;  out = s_wx;  }
  else if (y == 1) { pp = parts + PW_H;  N = FH; g = gh;  out = s_wh;  }
  else if (y == 2) { pp = parts + PW_MX; N = H;  g = gmx; out = s_wmx; }
  else             { pp = parts + PW_MH; N = H;  g = gmh; out = s_wmh; }
  if (c >= N) return;
  float s = 0.f;
  for (int p = 0; p < 8; ++p) s += pp[(size_t)p * N + c];
  out[c] = g[c] * rsqrtf(fmaxf(s, 1e-12f));
}

// ---------------- conversions ----------------
__global__ void cvt_h_kernel(const float* __restrict__ h_prev, ushort_t* __restrict__ hbf) {
  size_t idx = (size_t)blockIdx.x * 256 + threadIdx.x;   // < 8192*1952
  int row = (int)(idx / KP), col = (int)(idx % KP);
  float v = (col < H) ? h_prev[(size_t)row * H + col] : 0.f;
  hbf[idx] = f2bf(v);
}

__global__ void wmxn_kernel(const float* __restrict__ wmx, const float* __restrict__ s_wmx,
                            float* __restrict__ wmxn) {
  int idx = blockIdx.x * 256 + threadIdx.x;  // < 19200
  int i = idx / NP_A, j = idx - i * NP_A;
  wmxn[idx] = (j < H) ? wmx[i * H + j] * s_wmx[j] : 0.f;
}

// wmh [1900][1900] -> wmhT [1920][1952] bf16, transposed, pre-scaled
__global__ void wmhT_kernel(const float* __restrict__ wmh, const float* __restrict__ s_wmh,
                            ushort_t* __restrict__ wmhT) {
  __shared__ float tile[32][33];
  int n0 = blockIdx.x * 32, k0 = blockIdx.y * 32;
  int tx = threadIdx.x & 31, ty = threadIdx.x >> 5;   // ty 0..7
#pragma unroll
  for (int it = 0; it < 4; ++it) {
    int k = k0 + ty + it * 8, n = n0 + tx;
    float v = (k < H && n < H) ? wmh[(size_t)k * H + n] : 0.f;
    tile[ty + it * 8][tx] = v;   // tile[k_local][n_local]
  }
  __syncthreads();
#pragma unroll
  for (int it = 0; it < 4; ++it) {
    int n = n0 + ty + it * 8, k = k0 + tx;
    float v = tile[tx][ty + it * 8];
    float s = (n < H) ? s_wmh[n] : 0.f;
    wmhT[(size_t)n * KP + k] = f2bf(v * s);
  }
}

// wh [1900][7600] + wx [10][7600] -> whxT [7680][1952]: row n=4j+g <- col c=g*1900+j,
// k<1900: wh_n ; 1920<=k<1930: wx_n ; else 0. Pre-scaled.
__global__ void whxT_kernel(const float* __restrict__ wh, const float* __restrict__ wx,
                            const float* __restrict__ s_wh, const float* __restrict__ s_wx,
                            ushort_t* __restrict__ whxT) {
  __shared__ float tile[32][33];
  int c0 = blockIdx.x * 32, k0 = blockIdx.y * 32;
  int tx = threadIdx.x & 31, ty = threadIdx.x >> 5;
#pragma unroll
  for (int it = 0; it < 4; ++it) {
    int k = k0 + ty + it * 8, c = c0 + tx;
    float v = 0.f;
    if (c < FH) {
      if (k < H) v = wh[(size_t)k * FH + c] * s_wh[c];
      else if (k >= NP_A && k < NP_A + 10) v = wx[(size_t)(k - NP_A) * FH + c] * s_wx[c];
    }
    tile[ty + it * 8][tx] = v;   // tile[k_local][c_local]
  }
  __syncthreads();
#pragma unroll
  for (int it = 0; it < 4; ++it) {
    int c = c0 + ty + it * 8, k = k0 + tx;
    if (c < FH) {
      int g = c / H; int j = c - g * H; int n = 4 * j + g;
      whxT[(size_t)n * KP + k] = f2bf(tile[tx][ty + it * 8]);
    }
  }
}

__global__ void mext_tail_kernel(const float* __restrict__ inputs, ushort_t* __restrict__ m_ext) {
  int idx = blockIdx.x * 256 + threadIdx.x;   // < 8192*32
  int row = idx >> 5, c = idx & 31;
  float v = (c < 10) ? inputs[(size_t)row * 10 + c] : 0.f;
  m_ext[(size_t)row * KP + NP_A + c] = f2bf(v);
}

__global__ void whxT_tail_kernel(ushort_t* __restrict__ whxT) {
  int idx = blockIdx.x * 256 + threadIdx.x;   // < 80*1952
  whxT[(size_t)FH * KP + idx] = 0;
}

// ---------------- GEMM core: 128x128 tile, BK=32, NT, 16x16x32 bf16 MFMA ----------------
// LDS tile layout [128 rows][32 elems], 16B "halves" XOR-swizzled:
//   LDS slot (row, h_lds) holds global half h_g = h_lds ^ ((row>>1)&3)
// Staging via global_load_lds width-16: lane i of a wave-chunk (16 rows) covers
//   row = R + (i>>2), h_lds = i&3  ->  loads global half (i&3) ^ ((i>>3)&3).
//
// 2-phase double-buffered pipeline (T3 "minimum 2-phase"):
//   per K-step: issue STAGE(next tile -> other buffer), then ds_read+MFMA(current),
//   then ONE __syncthreads() (compiler emits s_waitcnt vmcnt(0) lgkmcnt(0) before
//   s_barrier -> per-wave stage writes AND per-wave LDS reads are drained before any
//   wave proceeds; dbuf invariant holds without inline asm).
//   Load latency overlaps the ds_read+MFMA of the same iteration instead of being
//   serially exposed between issue and compute.

__device__ __forceinline__ void mfma_step(const ushort_t* As, const ushort_t* Bs,
                                          int wm, int wn, int lo, int quad, int sw,
                                          f32x4 acc[4][4]) {
  bf16x8 af[4], bfv[4];
#pragma unroll
  for (int mf = 0; mf < 4; ++mf)
    af[mf] = *(const bf16x8*)(As + (wm + mf * 16 + lo) * BK + ((quad ^ sw) << 3));
#pragma unroll
  for (int nf = 0; nf < 4; ++nf)
    bfv[nf] = *(const bf16x8*)(Bs + (wn + nf * 16 + lo) * BK + ((quad ^ sw) << 3));
#pragma unroll
  for (int mf = 0; mf < 4; ++mf)
#pragma unroll
    for (int nf = 0; nf < 4; ++nf)
      acc[mf][nf] = __builtin_amdgcn_mfma_f32_16x16x32_bf16(af[mf], bfv[nf], acc[mf][nf], 0, 0, 0);
}

__device__ __forceinline__ void gemm_stage(const ushort_t*& gA0, const ushort_t*& gA1,
                                           const ushort_t*& gB0, const ushort_t*& gB1,
                                           ushort_t* lA0, ushort_t* lA1,
                                           ushort_t* lB0, ushort_t* lB1) {
  gl_lds16(gA0, lA0);
  gl_lds16(gA1, lA1);
  gl_lds16(gB0, lB0);
  gl_lds16(gB1, lB1);
  gA0 += BK; gA1 += BK; gB0 += BK; gB1 += BK;   // advance to next tile to stage
}

__device__ __forceinline__ void gemm_tile(const ushort_t* __restrict__ Ag,
                                          const ushort_t* __restrict__ Bg,
                                          int m0, int n0,
                                          char* smem,            // 32768 B: A0|B0|A1|B1
                                          f32x4 acc[4][4]) {
  ushort_t* As0 = (ushort_t*)(smem);
  ushort_t* Bs0 = (ushort_t*)(smem + 8192);
  ushort_t* As1 = (ushort_t*)(smem + 16384);
  ushort_t* Bs1 = (ushort_t*)(smem + 24576);

  const int tid = threadIdx.x;
  const int lane = tid & 63;
  const int quad = lane >> 4;
  const int lo = lane & 15;
  const int wave = tid >> 6;
  const int wm = (wave & 1) << 6;
  const int wn = (wave >> 1) << 6;
  const int sw = (lo >> 1) & 3;                       // read-side swizzle key

  // staging assignment: wave w loads rows [16w,16w+16) and [64+16w, 64+16w+16) of A and B
  const int cr = lane >> 2;                           // chunk-row 0..15
  const int hg = (lane & 3) ^ ((lane >> 3) & 3);      // swizzled global half 0..3
  const int r0 = wave * 16 + cr;
  const int r1 = 64 + wave * 16 + cr;
  const ushort_t* gA0 = Ag + (size_t)(m0 + r0) * KP + hg * 8;
  const ushort_t* gA1 = Ag + (size_t)(m0 + r1) * KP + hg * 8;
  const ushort_t* gB0 = Bg + (size_t)(n0 + r0) * KP + hg * 8;
  const ushort_t* gB1 = Bg + (size_t)(n0 + r1) * KP + hg * 8;
  ushort_t* lA0_0 = As0 + (wave * 16) * BK;           // wave-uniform LDS bases, buf0
  ushort_t* lA1_0 = As0 + (64 + wave * 16) * BK;
  ushort_t* lB0_0 = Bs0 + (wave * 16) * BK;
  ushort_t* lB1_0 = Bs0 + (64 + wave * 16) * BK;
  ushort_t* lA0_1 = As1 + (wave * 16) * BK;           // buf1
  ushort_t* lA1_1 = As1 + (64 + wave * 16) * BK;
  ushort_t* lB0_1 = Bs1 + (wave * 16) * BK;
  ushort_t* lB1_1 = Bs1 + (64 + wave * 16) * BK;

  // prologue: tile 0 -> buf0
  gemm_stage(gA0, gA1, gB0, gB1, lA0_0, lA1_0, lB0_0, lB1_0);
  __syncthreads();

  // steady state, pair-unrolled so every LDS address is compile-time static.
  // invariant at pair top: tile kt staged in buf0, pointers -> tile kt+1.
  for (int kt = 0; kt + 2 < KITERS; kt += 2) {
    gemm_stage(gA0, gA1, gB0, gB1, lA0_1, lA1_1, lB0_1, lB1_1);  // tile kt+1 -> buf1
    mfma_step(As0, Bs0, wm, wn, lo, quad, sw, acc);               // compute tile kt
    __syncthreads();   // drains this wave's vmcnt(0)+lgkmcnt(0); all waves synced
    gemm_stage(gA0, gA1, gB0, gB1, lA0_0, lA1_0, lB0_0, lB1_0);  // tile kt+2 -> buf0
    mfma_step(As1, Bs1, wm, wn, lo, quad, sw, acc);               // compute tile kt+1
    __syncthreads();
  }
  // KITERS odd: exactly one tile left, resident in buf0
  mfma_step(As0, Bs0, wm, wn, lo, quad, sw, acc);
  __syncthreads();   // also protects callers' smem reuse
}

// GEMM-A: P = h_prev_bf @ wmh_n^T ; epilogue m = (inputs·wmx_n) * P -> m_ext bf16
__global__ void __launch_bounds__(256) gemmA_kernel(const ushort_t* __restrict__ hbf,
                                                    const ushort_t* __restrict__ wmhT,
                                                    const float* __restrict__ inputs,
                                                    const float* __restrict__ wmxn,
                                                    ushort_t* __restrict__ m_ext) {
  __shared__ __align__(16) char smem[32768];
  f32x4 acc[4][4];
  f32x4 zv = {0.f, 0.f, 0.f, 0.f};
#pragma unroll
  for (int a = 0; a < 4; ++a)
#pragma unroll
    for (int bq = 0; bq < 4; ++bq) acc[a][bq] = zv;
  int m0 = blockIdx.x * 128, n0 = blockIdx.y * 128;
  gemm_tile(hbf, wmhT, m0, n0, smem, acc);
  float* inL  = (float*)smem;            // [128][10]
  float* wmxL = (float*)(smem + 5120);   // [10][128]
  for (int t = threadIdx.x; t < 1280; t += 256) {
    int r = t / 10, i = t - r * 10;
    inL[t] = inputs[(size_t)(m0 + r) * 10 + i];
  }
  for (int t = threadIdx.x; t < 1280; t += 256) {
    int i = t >> 7, c = t & 127;
    wmxL[t] = wmxn[i * NP_A + n0 + c];
  }
  __syncthreads();
  const int lane = threadIdx.x & 63, quad = lane >> 4, lo = lane & 15;
  const int wave = threadIdx.x >> 6, wm = (wave & 1) << 6, wn = (wave >> 1) << 6;
#pragma unroll
  for (int mf = 0; mf < 4; ++mf)
#pragma unroll
    for (int r = 0; r < 4; ++r) {
      int rl = wm + mf * 16 + quad * 4 + r;
      float inrow[10];
#pragma unroll
      for (int i = 0; i < 10; ++i) inrow[i] = inL[rl * 10 + i];
#pragma unroll
      for (int nf = 0; nf < 4; ++nf) {
        int cl = wn + nf * 16 + lo;
        float mx = 0.f;
#pragma unroll
        for (int i = 0; i < 10; ++i) mx += inrow[i] * wmxL[i * 128 + cl];
        float mv = acc[mf][nf][r] * mx;
        m_ext[(size_t)(m0 + rl) * KP + (n0 + cl)] = f2bf(mv);
      }
    }
}

// GEMM-B: z = m_ext @ whxT^T (+bias) ; epilogue: gates via shfl butterfly -> h, c
__global__ void __launch_bounds__(256) gemmB_kernel(const ushort_t* __restrict__ mext,
                                                    const ushort_t* __restrict__ whxT,
                                                    const float* __restrict__ bvec,
                                                    const float* __restrict__ c_prev,
                                                    float* __restrict__ hout,
                                                    float* __restrict__ cout) {
  __shared__ __align__(16) char smem[32768];
  f32x4 acc[4][4];
  f32x4 zv = {0.f, 0.f, 0.f, 0.f};
#pragma unroll
  for (int a = 0; a < 4; ++a)
#pragma unroll
    for (int bq = 0; bq < 4; ++bq) acc[a][bq] = zv;
  int m0 = blockIdx.x * 128, n0 = blockIdx.y * 128;
  gemm_tile(mext, whxT, m0, n0, smem, acc);
  const int lane = threadIdx.x & 63, quad = lane >> 4, lo = lane & 15;
  const int wave = threadIdx.x >> 6, wm = (wave & 1) << 6, wn = (wave >> 1) << 6;
#pragma unroll
  for (int nf = 0; nf < 4; ++nf) {
    int gn = n0 + wn + nf * 16 + lo;   // permuted col: n = 4j + g
    int j = gn >> 2, g = gn & 3;
    float bias = (j < H) ? bvec[g * H + j] : 0.f;
#pragma unroll
    for (int mf = 0; mf < 4; ++mf)
#pragma unroll
      for (int r = 0; r < 4; ++r) {
        float zs = acc[mf][nf][r] + bias;        // gate g
        float v1 = __shfl_xor(zs, 1);            // gate g^1
        float v2 = __shfl_xor(zs, 2);            // gate g^2
        float v3 = __shfl_xor(v1, 2);            // gate g^3
        if (g == r && j < H) {
          // pick(q): value for gate q is at t=q^g in {zs,v1,v2,v3}
          float zi, zf, zo, zu;
          { int t = 0 ^ g; zi = t == 0 ? zs : t == 1 ? v1 : t == 2 ? v2 : v3; }
          { int t = 1 ^ g; zf = t == 0 ? zs : t == 1 ? v1 : t == 2 ? v2 : v3; }
          { int t = 2 ^ g; zo = t == 0 ? zs : t == 1 ? v1 : t == 2 ? v2 : v3; }
          { int t = 3 ^ g; zu = t == 0 ? zs : t == 1 ? v1 : t == 2 ? v2 : v3; }
          float iv = 1.f / (1.f + __expf(-zi));
          float fv = 1.f / (1.f + __expf(-zf));
          float ov = 1.f / (1.f + __expf(-zo));
          float uv = tanhf(zu);
          int row = m0 + wm + mf * 16 + quad * 4 + r;
          size_t oidx = (size_t)row * H + j;
          float cp = c_prev[oidx];
          float cv = fv * cp + iv * uv;
          hout[oidx] = ov * tanhf(cv);
          cout[oidx] = cv;
        }
      }
  }
}

extern "C" void kernel_launch(void* const* d_in, const int* in_sizes, int n_in,
                              void* d_out, int out_size, void* d_ws, size_t ws_size,
                              hipStream_t stream) {
  const float* inputs = (const float*)d_in[0];
  const float* c_prev = (const float*)d_in[1];
  const float* h_prev = (const float*)d_in[2];
  const float* wx  = (const float*)d_in[3];
  const float* wh  = (const float*)d_in[4];
  const float* wmx = (const float*)d_in[5];
  const float* wmh = (const float*)d_in[6];
  const float* bv  = (const float*)d_in[7];
  const float* gx  = (const float*)d_in[8];
  const float* gh  = (const float*)d_in[9];
  const float* gmx = (const float*)d_in[10];
  const float* gmh = (const float*)d_in[11];

  char* ws = (char*)d_ws;
  float* s_wx  = (float*)(ws + OFF_SWX);
  float* s_wh  = (float*)(ws + OFF_SWH);
  float* s_wmx = (float*)(ws + OFF_SWMX);
  float* s_wmh = (float*)(ws + OFF_SWMH);
  float* wmxn  = (float*)(ws + OFF_WMXN);
  float* parts = (float*)(ws + OFF_PART);
  ushort_t* hbf   = (ushort_t*)(ws + OFF_HBF);
  ushort_t* m_ext = (ushort_t*)(ws + OFF_MEXT);
  ushort_t* wmhT  = (ushort_t*)(ws + OFF_WMHT);
  ushort_t* whxT  = (ushort_t*)(ws + OFF_WHXT);

  float* hout = (float*)d_out;
  float* cout = hout + (size_t)BATCH * H;

  colsum_partial_kernel<<<dim3(30, 4, 8), 256, 0, stream>>>(wx, wh, wmx, wmh, parts);
  scales_final_kernel<<<dim3(30, 4), 256, 0, stream>>>(parts, gx, gh, gmx, gmh,
                                                       s_wx, s_wh, s_wmx, s_wmh);
  cvt_h_kernel<<<62464, 256, 0, stream>>>(h_prev, hbf);
  wmxn_kernel<<<75, 256, 0, stream>>>(wmx, s_wmx, wmxn);
  wmhT_kernel<<<dim3(60, 61), 256, 0, stream>>>(wmh, s_wmh, wmhT);
  whxT_kernel<<<dim3(238, 61), 256, 0, stream>>>(wh, wx, s_wh, s_wx, whxT);
  mext_tail_kernel<<<1024, 256, 0, stream>>>(inputs, m_ext);
  whxT_tail_kernel<<<610, 256, 0, stream>>>(whxT);
  gemmA_kernel<<<dim3(64, 15), 256, 0, stream>>>(hbf, wmhT, inputs, wmxn, m_ext);
  gemmB_kernel<<<dim3(64, 60), 256, 0, stream>>>(m_ext, whxT, bv, c_prev, hout, cout);
}

// Round 2
// 1093.449 us; speedup vs baseline: 1.1335x; 1.1335x over previous
//
#include <hip/hip_runtime.h>

typedef unsigned short ushort_t;
typedef short bf16x8 __attribute__((ext_vector_type(8)));
typedef float f32x4 __attribute__((ext_vector_type(4)));

#define H 1900
#define FH 7600      // 4*H
#define BATCH 8192
#define KP 1952      // padded K stride: 1900 m | 20 pad | 10 inputs | 22 pad (mult of 32)
#define NP_A 1920    // padded N for gemmA (m columns)
#define NB 7680      // padded row count of whxT
#define BK 32
#define KITERS (KP / BK)   // 61

// 8-phase gemmB geometry
#define NKT 30       // full 64-wide K-tiles (30*64 = 1920), tail = 32

// ---- ws layout (bytes) ----
static const size_t OFF_SWX  = 0;          // 7600 f32
static const size_t OFF_SWH  = 32768;      // 7600 f32
static const size_t OFF_SWMX = 65536;      // 1900 f32
static const size_t OFF_SWMH = 73728;      // 1900 f32
static const size_t OFF_WMXN = 81920;      // 10*1920 f32 (pre-scaled wmx_n)
static const size_t OFF_PART = 163840;     // partial colsums: 8*(7600+7600+1900+1900) f32
static const size_t OFF_HBF  = 786432;                   // h_prev bf16 [8192][1952]
static const size_t OFF_MEXT = OFF_HBF + 31981568;       // m_ext bf16 [8192][1952]
static const size_t OFF_WMHT = OFF_MEXT + 31981568;      // wmh_n^T bf16 [1920][1952]
static const size_t OFF_WHXT = OFF_WMHT + 7495680;       // [wh_n|wx_n]^T perm bf16 [7680][1952]
// end = OFF_WHXT + 29982720 ≈ 97.5 MB

// partial-sum sub-offsets (in floats, within OFF_PART)
#define PW_X  0
#define PW_H  60800
#define PW_MX 121600
#define PW_MH 136800

#define BAR() __builtin_amdgcn_s_barrier()
#define PRIO1 __builtin_amdgcn_s_setprio(1)
#define PRIO0 __builtin_amdgcn_s_setprio(0)
#define WAIT_LGKM0 asm volatile("s_waitcnt lgkmcnt(0)" ::: "memory")
#define WAIT_VM(N) asm volatile("s_waitcnt vmcnt(" #N ")" ::: "memory")

__device__ __forceinline__ ushort_t f2bf(float x) {
  unsigned u = __float_as_uint(x);
  return (ushort_t)((u + 0x7fffu + ((u >> 16) & 1u)) >> 16);
}

// async global->LDS, 16 B per lane; LDS dest = wave-uniform base (+ lane*16 by HW)
__device__ __forceinline__ void gl_lds16(const ushort_t* g, ushort_t* lds) {
  __builtin_amdgcn_global_load_lds(
      (const __attribute__((address_space(1))) unsigned int*)(g),
      (__attribute__((address_space(3))) unsigned int*)(lds), 16, 0, 0);
}

// ---------------- scales: per-column l2-norm partials, then gain*rsqrt ----------------
__global__ void colsum_partial_kernel(const float* __restrict__ wx, const float* __restrict__ wh,
                                      const float* __restrict__ wmx, const float* __restrict__ wmh,
                                      float* __restrict__ parts) {
  int c = blockIdx.x * 256 + threadIdx.x;
  int y = blockIdx.y, p = blockIdx.z;
  const float* W; int K, N; float* out;
  if (y == 0)      { W = wx;  K = 10;   N = FH; out = parts + PW_X  + (size_t)p * FH; }
  else if (y == 1) { W = wh;  K = 1900; N = FH; out = parts + PW_H  + (size_t)p * FH; }
  else if (y == 2) { W = wmx; K = 10;   N = H;  out = parts + PW_MX + (size_t)p * H;  }
  else             { W = wmh; K = 1900; N = H;  out = parts + PW_MH + (size_t)p * H;  }
  if (c >= N) return;
  int rp = (K + 7) / 8;
  int r0 = p * rp, r1 = r0 + rp; if (r1 > K) r1 = K;
  float s = 0.f;
  for (int r = r0; r < r1; ++r) { float v = W[(size_t)r * N + c]; s += v * v; }
  out[c] = s;
}

__global__ void scales_final_kernel(const float* __restrict__ parts,
                                    const float* __restrict__ gx, const float* __restrict__ gh,
                                    const float* __restrict__ gmx, const float* __restrict__ gmh,
                                    float* __restrict__ s_wx, float* __restrict__ s_wh,
                                    float* __restrict__ s_wmx, float* __restrict__ s_wmh) {
  int c = blockIdx.x * 256 + threadIdx.x;
  int y = blockIdx.y;
  const float* pp; int N; const float* g; float* out;
  if (y == 0)      { pp = parts + PW_X;  N = FH; g = gx;  out = s_wx;  }
  else if (y == 1) { pp = parts + PW_H;  N = FH; g = gh;  out = s_wh;  }
  else if (y == 2) { pp = parts + PW_MX; N = H;  g = gmx; out = s_wmx; }
  else             { pp = parts + PW_MH; N = H;  g = gmh; out = s_wmh; }
  if (c >= N) return;
  float s = 0.f;
  for (int p = 0; p < 8; ++p) s += pp[(size_t)p * N + c];
  out[c] = g[c] * rsqrtf(fmaxf(s, 1e-12f));
}

// ---------------- conversions ----------------
__global__ void cvt_h_kernel(const float* __restrict__ h_prev, ushort_t* __restrict__ hbf) {
  size_t idx = (size_t)blockIdx.x * 256 + threadIdx.x;   // < 8192*1952
  int row = (int)(idx / KP), col = (int)(idx % KP);
  float v = (col < H) ? h_prev[(size_t)row * H + col] : 0.f;
  hbf[idx] = f2bf(v);
}

__global__ void wmxn_kernel(const float* __restrict__ wmx, const float* __restrict__ s_wmx,
                            float* __restrict__ wmxn) {
  int idx = blockIdx.x * 256 + threadIdx.x;  // < 19200
  int i = idx / NP_A, j = idx - i * NP_A;
  wmxn[idx] = (j < H) ? wmx[i * H + j] * s_wmx[j] : 0.f;
}

// wmh [1900][1900] -> wmhT [1920][1952] bf16, transposed, pre-scaled
__global__ void wmhT_kernel(const float* __restrict__ wmh, const float* __restrict__ s_wmh,
                            ushort_t* __restrict__ wmhT) {
  __shared__ float tile[32][33];
  int n0 = blockIdx.x * 32, k0 = blockIdx.y * 32;
  int tx = threadIdx.x & 31, ty = threadIdx.x >> 5;   // ty 0..7
#pragma unroll
  for (int it = 0; it < 4; ++it) {
    int k = k0 + ty + it * 8, n = n0 + tx;
    float v = (k < H && n < H) ? wmh[(size_t)k * H + n] : 0.f;
    tile[ty + it * 8][tx] = v;   // tile[k_local][n_local]
  }
  __syncthreads();
#pragma unroll
  for (int it = 0; it < 4; ++it) {
    int n = n0 + ty + it * 8, k = k0 + tx;
    float v = tile[tx][ty + it * 8];
    float s = (n < H) ? s_wmh[n] : 0.f;
    wmhT[(size_t)n * KP + k] = f2bf(v * s);
  }
}

// wh [1900][7600] + wx [10][7600] -> whxT [7680][1952]: row n=4j+g <- col c=g*1900+j,
// k<1900: wh_n ; 1920<=k<1930: wx_n ; else 0. Pre-scaled.
__global__ void whxT_kernel(const float* __restrict__ wh, const float* __restrict__ wx,
                            const float* __restrict__ s_wh, const float* __restrict__ s_wx,
                            ushort_t* __restrict__ whxT) {
  __shared__ float tile[32][33];
  int c0 = blockIdx.x * 32, k0 = blockIdx.y * 32;
  int tx = threadIdx.x & 31, ty = threadIdx.x >> 5;
#pragma unroll
  for (int it = 0; it < 4; ++it) {
    int k = k0 + ty + it * 8, c = c0 + tx;
    float v = 0.f;
    if (c < FH) {
      if (k < H) v = wh[(size_t)k * FH + c] * s_wh[c];
      else if (k >= NP_A && k < NP_A + 10) v = wx[(size_t)(k - NP_A) * FH + c] * s_wx[c];
    }
    tile[ty + it * 8][tx] = v;   // tile[k_local][c_local]
  }
  __syncthreads();
#pragma unroll
  for (int it = 0; it < 4; ++it) {
    int c = c0 + ty + it * 8, k = k0 + tx;
    if (c < FH) {
      int g = c / H; int j = c - g * H; int n = 4 * j + g;
      whxT[(size_t)n * KP + k] = f2bf(tile[tx][ty + it * 8]);
    }
  }
}

__global__ void mext_tail_kernel(const float* __restrict__ inputs, ushort_t* __restrict__ m_ext) {
  int idx = blockIdx.x * 256 + threadIdx.x;   // < 8192*32
  int row = idx >> 5, c = idx & 31;
  float v = (c < 10) ? inputs[(size_t)row * 10 + c] : 0.f;
  m_ext[(size_t)row * KP + NP_A + c] = f2bf(v);
}

__global__ void whxT_tail_kernel(ushort_t* __restrict__ whxT) {
  int idx = blockIdx.x * 256 + threadIdx.x;   // < 80*1952
  whxT[(size_t)FH * KP + idx] = 0;
}

// ============ gemmA core (round-0 proven): 128x128 tile, BK=32, single-buffer ============
// LDS tile layout [128 rows][32 elems], 16B halves XOR-swizzled:
//   LDS slot (row, h_lds) holds global half h_g = h_lds ^ ((row>>1)&3)
__device__ __forceinline__ void gemm_tile128(const ushort_t* __restrict__ Ag,
                                             const ushort_t* __restrict__ Bg,
                                             int m0, int n0,
                                             ushort_t* As, ushort_t* Bs,
                                             f32x4 acc[4][4]) {
  const int tid = threadIdx.x;
  const int lane = tid & 63;
  const int quad = lane >> 4;
  const int lo = lane & 15;
  const int wave = tid >> 6;
  const int wm = (wave & 1) << 6;
  const int wn = (wave >> 1) << 6;
  const int sw = (lo >> 1) & 3;

  const int cr = lane >> 2;
  const int hg = (lane & 3) ^ ((lane >> 3) & 3);
  const int r0 = wave * 16 + cr;
  const int r1 = 64 + wave * 16 + cr;
  const ushort_t* gA0 = Ag + (size_t)(m0 + r0) * KP + hg * 8;
  const ushort_t* gA1 = Ag + (size_t)(m0 + r1) * KP + hg * 8;
  const ushort_t* gB0 = Bg + (size_t)(n0 + r0) * KP + hg * 8;
  const ushort_t* gB1 = Bg + (size_t)(n0 + r1) * KP + hg * 8;
  ushort_t* lA0 = As + (wave * 16) * BK;
  ushort_t* lA1 = As + (64 + wave * 16) * BK;
  ushort_t* lB0 = Bs + (wave * 16) * BK;
  ushort_t* lB1 = Bs + (64 + wave * 16) * BK;

  for (int kt = 0; kt < KITERS; ++kt) {
    __syncthreads();
    gl_lds16(gA0, lA0);
    gl_lds16(gA1, lA1);
    gl_lds16(gB0, lB0);
    gl_lds16(gB1, lB1);
    __syncthreads();
    bf16x8 af[4], bfv[4];
#pragma unroll
    for (int mf = 0; mf < 4; ++mf)
      af[mf] = *(const bf16x8*)(As + (wm + mf * 16 + lo) * BK + ((quad ^ sw) << 3));
#pragma unroll
    for (int nf = 0; nf < 4; ++nf)
      bfv[nf] = *(const bf16x8*)(Bs + (wn + nf * 16 + lo) * BK + ((quad ^ sw) << 3));
#pragma unroll
    for (int mf = 0; mf < 4; ++mf)
#pragma unroll
      for (int nf = 0; nf < 4; ++nf)
        acc[mf][nf] = __builtin_amdgcn_mfma_f32_16x16x32_bf16(af[mf], bfv[nf], acc[mf][nf], 0, 0, 0);
    gA0 += BK; gA1 += BK; gB0 += BK; gB1 += BK;
  }
}

// GEMM-A: P = h_prev_bf @ wmh_n^T ; epilogue m = (inputs·wmx_n) * P -> m_ext bf16
__global__ void __launch_bounds__(256) gemmA_kernel(const ushort_t* __restrict__ hbf,
                                                    const ushort_t* __restrict__ wmhT,
                                                    const float* __restrict__ inputs,
                                                    const float* __restrict__ wmxn,
                                                    ushort_t* __restrict__ m_ext) {
  __shared__ __align__(16) char smem[16384];
  ushort_t* As = (ushort_t*)smem;
  ushort_t* Bs = (ushort_t*)(smem + 8192);
  f32x4 acc[4][4];
  f32x4 zv = {0.f, 0.f, 0.f, 0.f};
#pragma unroll
  for (int a = 0; a < 4; ++a)
#pragma unroll
    for (int bq = 0; bq < 4; ++bq) acc[a][bq] = zv;
  int m0 = blockIdx.x * 128, n0 = blockIdx.y * 128;
  gemm_tile128(hbf, wmhT, m0, n0, As, Bs, acc);
  __syncthreads();
  float* inL  = (float*)smem;            // [128][10]
  float* wmxL = (float*)(smem + 5120);   // [10][128]
  for (int t = threadIdx.x; t < 1280; t += 256) {
    int r = t / 10, i = t - r * 10;
    inL[t] = inputs[(size_t)(m0 + r) * 10 + i];
  }
  for (int t = threadIdx.x; t < 1280; t += 256) {
    int i = t >> 7, c = t & 127;
    wmxL[t] = wmxn[i * NP_A + n0 + c];
  }
  __syncthreads();
  const int lane = threadIdx.x & 63, quad = lane >> 4, lo = lane & 15;
  const int wave = threadIdx.x >> 6, wm = (wave & 1) << 6, wn = (wave >> 1) << 6;
#pragma unroll
  for (int mf = 0; mf < 4; ++mf)
#pragma unroll
    for (int r = 0; r < 4; ++r) {
      int rl = wm + mf * 16 + quad * 4 + r;
      float inrow[10];
#pragma unroll
      for (int i = 0; i < 10; ++i) inrow[i] = inL[rl * 10 + i];
#pragma unroll
      for (int nf = 0; nf < 4; ++nf) {
        int cl = wn + nf * 16 + lo;
        float mx = 0.f;
#pragma unroll
        for (int i = 0; i < 10; ++i) mx += inrow[i] * wmxL[i * 128 + cl];
        float mv = acc[mf][nf][r] * mx;
        m_ext[(size_t)(m0 + rl) * KP + (n0 + cl)] = f2bf(mv);
      }
    }
}

// ============ gemmB: 256x256 tile, BK=64, 8 waves, 4-phase/K-tile counted-vmcnt ============
// LDS per buffer: A[256][64] (32KB) + B[256][64] (32KB); 2 buffers = 128KB dynamic.
// Swizzle: 16B slot s of row r stored at slot s^(r&7); gl_lds dest linear, source
// pre-swizzled per-lane (rule #21). Conflict: per 16-lane group reads spread over
// all 8 slots (2 lanes each) -> minimum-cycle b128 reads.
//
// Per K-tile T (buffers cur=T&1): phases
//  P1: read A(cur, mh=0) 8x b128 + B(cur, nh=0) 4x ; stage A1(T+1)->nxt ; BAR;lgkm0;16 MFMA Q(0,0);BAR
//  P2: read B(cur, nh=1) 4x                        ; (no stage)         ; BAR;lgkm0;16 MFMA Q(0,1);BAR
//  P3: read A(cur, mh=1) 8x                        ; stage B0(T+2)->cur ; BAR;lgkm0;16 MFMA Q(1,1);BAR
//  P4: (no reads)                 ; stage A0(T+2)->cur, B1(T+2)->cur ; vmcnt(6); BAR; 16 MFMA Q(1,0); BAR
// Overwrite hazards: A0 region last read P3 (stage P4, after P3 barrier); B0 last read P2
// (stage P3); B1 last read P2 (stage P4); A1(T+1) targets other buffer, whose A1 region was
// last read at P3 of T-1. vmcnt(6) leaves exactly {B0,A0,B1}(T+2) in flight -> tile T+1 resident.

__device__ __forceinline__ void stage_half(const ushort_t* __restrict__ G, int Rg, int kb,
                                           ushort_t* L, int tid) {
  const int wave = tid >> 6;
#pragma unroll
  for (int q = 0; q < 2; ++q) {
    const int idx = q * 512 + tid;
    const int r = idx >> 3, s = idx & 7;
    const int gs = s ^ (r & 7);
    gl_lds16(G + (size_t)(Rg + r) * KP + kb + gs * 8,
             L + (size_t)(q * 512 + wave * 64) * 8);
  }
}

__device__ __forceinline__ void read_Ahalf(const ushort_t* A, int wmL, int lo, int mh,
                                           int sw0, int sw1, bf16x8 af[8]) {
#pragma unroll
  for (int mf = 0; mf < 4; ++mf) {
    const ushort_t* p = A + ((wmL + mh * 64 + mf * 16 + lo) << 6);
    af[mf * 2 + 0] = *(const bf16x8*)(p + sw0);
    af[mf * 2 + 1] = *(const bf16x8*)(p + sw1);
  }
}

__device__ __forceinline__ void read_Bhalf(const ushort_t* B, int wnL, int lo, int nh,
                                           int sw0, int sw1, bf16x8 bf[4]) {
#pragma unroll
  for (int nf = 0; nf < 2; ++nf) {
    const ushort_t* p = B + ((wnL + nh * 32 + nf * 16 + lo) << 6);
    bf[nf * 2 + 0] = *(const bf16x8*)(p + sw0);
    bf[nf * 2 + 1] = *(const bf16x8*)(p + sw1);
  }
}

__device__ __forceinline__ void mfma_quad(const bf16x8 af[8], const bf16x8 bf[4],
                                          f32x4 acc[8][4], int mh, int nh) {
#pragma unroll
  for (int mf = 0; mf < 4; ++mf)
#pragma unroll
    for (int nf = 0; nf < 2; ++nf) {
      f32x4 c = acc[mh * 4 + mf][nh * 2 + nf];
      c = __builtin_amdgcn_mfma_f32_16x16x32_bf16(af[mf * 2 + 0], bf[nf * 2 + 0], c, 0, 0, 0);
      c = __builtin_amdgcn_mfma_f32_16x16x32_bf16(af[mf * 2 + 1], bf[nf * 2 + 1], c, 0, 0, 0);
      acc[mh * 4 + mf][nh * 2 + nf] = c;
    }
}

// MODE: 0=steady (stage T+1/T+2, vmcnt(6)), 1=T=NKT-2 (stage only A1(T+1), vmcnt(0)), 2=last
template <int MODE>
__device__ __forceinline__ void b8_iter(const ushort_t* __restrict__ Ag,
                                        const ushort_t* __restrict__ Bg,
                                        int m0, int n0, int T,
                                        ushort_t* Acur, ushort_t* Bcur,
                                        ushort_t* Anxt, ushort_t* Bnxt,
                                        int tid, int lo, int wmL, int wnL,
                                        int sw0, int sw1, f32x4 acc[8][4]) {
  bf16x8 af[8], b0f[4], b1f[4];
  // P1
  read_Ahalf(Acur, wmL, lo, 0, sw0, sw1, af);
  read_Bhalf(Bcur, wnL, lo, 0, sw0, sw1, b0f);
  if (MODE <= 1) stage_half(Ag, m0 + 128, (T + 1) * 64, Anxt + 8192, tid);
  BAR(); WAIT_LGKM0;
  PRIO1; mfma_quad(af, b0f, acc, 0, 0); PRIO0;
  BAR();
  // P2
  read_Bhalf(Bcur, wnL, lo, 1, sw0, sw1, b1f);
  BAR(); WAIT_LGKM0;
  PRIO1; mfma_quad(af, b1f, acc, 0, 1); PRIO0;
  BAR();
  // P3
  read_Ahalf(Acur, wmL, lo, 1, sw0, sw1, af);
  if (MODE == 0) stage_half(Bg, n0, (T + 2) * 64, Bcur, tid);
  BAR(); WAIT_LGKM0;
  PRIO1; mfma_quad(af, b1f, acc, 1, 1); PRIO0;
  BAR();
  // P4
  if (MODE == 0) {
    stage_half(Ag, m0, (T + 2) * 64, Acur, tid);
    stage_half(Bg, n0 + 128, (T + 2) * 64, Bcur + 8192, tid);
    WAIT_VM(6);
  } else if (MODE == 1) {
    WAIT_VM(0);
  }
  BAR();
  PRIO1; mfma_quad(af, b0f, acc, 1, 0); PRIO0;
  BAR();
}

__global__ void __launch_bounds__(512, 2)
gemmB8_kernel(const ushort_t* __restrict__ mext, const ushort_t* __restrict__ whxT,
              const float* __restrict__ bvec, const float* __restrict__ c_prev,
              float* __restrict__ hout, float* __restrict__ cout) {
  extern __shared__ __align__(16) char smem[];
  ushort_t* As0 = (ushort_t*)smem;                 // buf0 A [256][64]
  ushort_t* Bs0 = (ushort_t*)(smem + 32768);       // buf0 B
  ushort_t* As1 = (ushort_t*)(smem + 65536);       // buf1 A
  ushort_t* Bs1 = (ushort_t*)(smem + 98304);       // buf1 B

  const int tid = threadIdx.x;
  const int lane = tid & 63;
  const int lo = lane & 15, quad = lane >> 4;
  const int wave = tid >> 6;
  const int wmL = (wave & 1) << 7;     // 0 / 128
  const int wnL = (wave >> 1) << 6;    // 0 / 64 / 128 / 192
  const int sw0 = ((quad ^ (lo & 7)) << 3);
  const int sw1 = (((4 | quad) ^ (lo & 7)) << 3);

  // XCD-bijective swizzle: 960 blocks = 8 XCDs x 120
  int bid = blockIdx.x;
  int swz = (bid & 7) * 120 + (bid >> 3);
  int mt = swz & 31, nt = swz >> 5;    // 32 m-tiles x 30 n-tiles
  int m0 = mt << 8, n0 = nt << 8;

  f32x4 acc[8][4];
  f32x4 zv = {0.f, 0.f, 0.f, 0.f};
#pragma unroll
  for (int a = 0; a < 8; ++a)
#pragma unroll
    for (int bq = 0; bq < 4; ++bq) acc[a][bq] = zv;

  const ushort_t* Ag = mext;
  const ushort_t* Bg = whxT;

  // prologue: full tile 0 -> buf0, then {B0,A0,B1}(1) -> buf1 (A1(1) issued at P1 of T=0)
  stage_half(Ag, m0,       0,  As0,        tid);
  stage_half(Bg, n0,       0,  Bs0,        tid);
  stage_half(Ag, m0 + 128, 0,  As0 + 8192, tid);
  stage_half(Bg, n0 + 128, 0,  Bs0 + 8192, tid);
  stage_half(Bg, n0,       64, Bs1,        tid);
  stage_half(Ag, m0,       64, As1,        tid);
  stage_half(Bg, n0 + 128, 64, Bs1 + 8192, tid);
  WAIT_VM(6);   // tile 0 resident; {B0,A0,B1}(1) in flight
  BAR();

  for (int T = 0; T < NKT - 2; T += 2) {
    b8_iter<0>(Ag, Bg, m0, n0, T,     As0, Bs0, As1, Bs1, tid, lo, wmL, wnL, sw0, sw1, acc);
    b8_iter<0>(Ag, Bg, m0, n0, T + 1, As1, Bs1, As0, Bs0, tid, lo, wmL, wnL, sw0, sw1, acc);
  }
  b8_iter<1>(Ag, Bg, m0, n0, NKT - 2, As0, Bs0, As1, Bs1, tid, lo, wmL, wnL, sw0, sw1, acc);
  b8_iter<2>(Ag, Bg, m0, n0, NKT - 1, As1, Bs1, As0, Bs0, tid, lo, wmL, wnL, sw0, sw1, acc);

  // ---- tail: K columns 1920..1951 (32 wide), staged into buf0 [256][32], swz s^(r&3) ----
  {
    const int wavei = tid >> 6;
#pragma unroll
    for (int q = 0; q < 2; ++q) {
      const int idx = q * 512 + tid;
      const int r = idx >> 2, s = idx & 3;
      const int gs = s ^ (r & 3);
      gl_lds16(Ag + (size_t)(m0 + r) * KP + 1920 + gs * 8,
               As0 + (size_t)(q * 512 + wavei * 64) * 8);
    }
#pragma unroll
    for (int q = 0; q < 2; ++q) {
      const int idx = q * 512 + tid;
      const int r = idx >> 2, s = idx & 3;
      const int gs = s ^ (r & 3);
      gl_lds16(Bg + (size_t)(n0 + r) * KP + 1920 + gs * 8,
               Bs0 + (size_t)(q * 512 + wavei * 64) * 8);
    }
    WAIT_VM(0);
    BAR();
    const int swt = ((quad ^ (lo & 3)) << 3);
    bf16x8 a2[8], b2[4];
#pragma unroll
    for (int mf = 0; mf < 8; ++mf)
      a2[mf] = *(const bf16x8*)(As0 + ((wmL + mf * 16 + lo) << 5) + swt);
#pragma unroll
    for (int nf = 0; nf < 4; ++nf)
      b2[nf] = *(const bf16x8*)(Bs0 + ((wnL + nf * 16 + lo) << 5) + swt);
#pragma unroll
    for (int mf = 0; mf < 8; ++mf)
#pragma unroll
      for (int nf = 0; nf < 4; ++nf)
        acc[mf][nf] = __builtin_amdgcn_mfma_f32_16x16x32_bf16(a2[mf], b2[nf], acc[mf][nf], 0, 0, 0);
  }

  // ---- epilogue: gates via shfl butterfly -> h, c ----
#pragma unroll
  for (int nf = 0; nf < 4; ++nf) {
    int gn = n0 + wnL + nf * 16 + lo;   // permuted col: n = 4j + g
    int j = gn >> 2, g = gn & 3;
    float bias = (j < H) ? bvec[g * H + j] : 0.f;
#pragma unroll
    for (int mf = 0; mf < 8; ++mf)
#pragma unroll
      for (int r = 0; r < 4; ++r) {
        float zs = acc[mf][nf][r] + bias;        // gate g
        float v1 = __shfl_xor(zs, 1);            // gate g^1
        float v2 = __shfl_xor(zs, 2);            // gate g^2
        float v3 = __shfl_xor(v1, 2);            // gate g^3
        if (g == r && j < H) {
          float zi, zf, zo, zu;
          { int t = 0 ^ g; zi = t == 0 ? zs : t == 1 ? v1 : t == 2 ? v2 : v3; }
          { int t = 1 ^ g; zf = t == 0 ? zs : t == 1 ? v1 : t == 2 ? v2 : v3; }
          { int t = 2 ^ g; zo = t == 0 ? zs : t == 1 ? v1 : t == 2 ? v2 : v3; }
          { int t = 3 ^ g; zu = t == 0 ? zs : t == 1 ? v1 : t == 2 ? v2 : v3; }
          float iv = 1.f / (1.f + __expf(-zi));
          float fv = 1.f / (1.f + __expf(-zf));
          float ov = 1.f / (1.f + __expf(-zo));
          float uv = tanhf(zu);
          int row = m0 + wmL + mf * 16 + quad * 4 + r;
          size_t oidx = (size_t)row * H + j;
          float cp = c_prev[oidx];
          float cv = fv * cp + iv * uv;
          hout[oidx] = ov * tanhf(cv);
          cout[oidx] = cv;
        }
      }
  }
}

extern "C" void kernel_launch(void* const* d_in, const int* in_sizes, int n_in,
                              void* d_out, int out_size, void* d_ws, size_t ws_size,
                              hipStream_t stream) {
  const float* inputs = (const float*)d_in[0];
  const float* c_prev = (const float*)d_in[1];
  const float* h_prev = (const float*)d_in[2];
  const float* wx  = (const float*)d_in[3];
  const float* wh  = (const float*)d_in[4];
  const float* wmx = (const float*)d_in[5];
  const float* wmh = (const float*)d_in[6];
  const float* bv  = (const float*)d_in[7];
  const float* gx  = (const float*)d_in[8];
  const float* gh  = (const float*)d_in[9];
  const float* gmx = (const float*)d_in[10];
  const float* gmh = (const float*)d_in[11];

  char* ws = (char*)d_ws;
  float* s_wx  = (float*)(ws + OFF_SWX);
  float* s_wh  = (float*)(ws + OFF_SWH);
  float* s_wmx = (float*)(ws + OFF_SWMX);
  float* s_wmh = (float*)(ws + OFF_SWMH);
  float* wmxn  = (float*)(ws + OFF_WMXN);
  float* parts = (float*)(ws + OFF_PART);
  ushort_t* hbf   = (ushort_t*)(ws + OFF_HBF);
  ushort_t* m_ext = (ushort_t*)(ws + OFF_MEXT);
  ushort_t* wmhT  = (ushort_t*)(ws + OFF_WMHT);
  ushort_t* whxT  = (ushort_t*)(ws + OFF_WHXT);

  float* hout = (float*)d_out;
  float* cout = hout + (size_t)BATCH * H;

  static bool attr_set = false;
  if (!attr_set) {
    hipFuncSetAttribute(reinterpret_cast<const void*>(&gemmB8_kernel),
                        hipFuncAttributeMaxDynamicSharedMemorySize, 131072);
    attr_set = true;
  }

  colsum_partial_kernel<<<dim3(30, 4, 8), 256, 0, stream>>>(wx, wh, wmx, wmh, parts);
  scales_final_kernel<<<dim3(30, 4), 256, 0, stream>>>(parts, gx, gh, gmx, gmh,
                                                       s_wx, s_wh, s_wmx, s_wmh);
  cvt_h_kernel<<<62464, 256, 0, stream>>>(h_prev, hbf);
  wmxn_kernel<<<75, 256, 0, stream>>>(wmx, s_wmx, wmxn);
  wmhT_kernel<<<dim3(60, 61), 256, 0, stream>>>(wmh, s_wmh, wmhT);
  whxT_kernel<<<dim3(238, 61), 256, 0, stream>>>(wh, wx, s_wh, s_wx, whxT);
  mext_tail_kernel<<<1024, 256, 0, stream>>>(inputs, m_ext);
  whxT_tail_kernel<<<610, 256, 0, stream>>>(whxT);
  gemmA_kernel<<<dim3(64, 15), 256, 0, stream>>>(hbf, wmhT, inputs, wmxn, m_ext);
  gemmB8_kernel<<<dim3(960), 512, 131072, stream>>>(m_ext, whxT, bv, c_prev, hout, cout);
}

// Round 3
// 1052.052 us; speedup vs baseline: 1.1781x; 1.0393x over previous
//
#include <hip/hip_runtime.h>

typedef unsigned short ushort_t;
typedef short bf16x8 __attribute__((ext_vector_type(8)));
typedef float f32x4 __attribute__((ext_vector_type(4)));

#define H 1900
#define FH 7600      // 4*H
#define BATCH 8192
#define KP 1952      // padded K stride for hbf/wmhT (gemmA operands)
#define NP_A 1920    // padded N for gemmA (m columns)
#define NB 7680      // padded row count of whxT
#define BK 32
#define KITERS (KP / BK)   // 61

// gemmB tiled-layout geometry: panel = 256 rows; K split into 30 full 64-tiles + 32 tail
#define NKT 30
#define KT_U 16384         // ushorts per full K-tile slab (256*64)
#define TAIL_U 491520      // NKT*KT_U : offset of tail slab (256*32)
#define PANEL_U 499712     // TAIL_U + 256*32 : ushorts per panel

// ---- ws layout (bytes) ----
static const size_t OFF_SWX  = 0;          // 7600 f32
static const size_t OFF_SWH  = 32768;      // 7600 f32
static const size_t OFF_SWMX = 65536;      // 1900 f32
static const size_t OFF_SWMH = 73728;      // 1900 f32
static const size_t OFF_WMXN = 81920;      // 10*1920 f32 (pre-scaled wmx_n)
static const size_t OFF_PART = 163840;     // partial colsums: 8*(7600+7600+1900+1900) f32
static const size_t OFF_HBF  = 786432;                   // h_prev bf16 [8192][1952] (KP layout)
static const size_t OFF_MEXT = OFF_HBF + 31981568;       // m_ext bf16 TILED: 32 panels * PANEL_U
static const size_t OFF_WMHT = OFF_MEXT + 31981568;      // wmh_n^T bf16 [1920][1952] (KP layout)
static const size_t OFF_WHXT = OFF_WMHT + 7495680;       // whxT bf16 TILED: 30 panels * PANEL_U
// end = OFF_WHXT + 29982720 ≈ 97.5 MB

// partial-sum sub-offsets (in floats, within OFF_PART)
#define PW_X  0
#define PW_H  60800
#define PW_MX 121600
#define PW_MH 136800

#define BAR() __builtin_amdgcn_s_barrier()
#define PRIO1 __builtin_amdgcn_s_setprio(1)
#define PRIO0 __builtin_amdgcn_s_setprio(0)
#define WAIT_LGKM0 asm volatile("s_waitcnt lgkmcnt(0)" ::: "memory")
#define WAIT_VM(N) asm volatile("s_waitcnt vmcnt(" #N ")" ::: "memory")

__device__ __forceinline__ ushort_t f2bf(float x) {
  unsigned u = __float_as_uint(x);
  return (ushort_t)((u + 0x7fffu + ((u >> 16) & 1u)) >> 16);
}

// async global->LDS, 16 B per lane; LDS dest = wave-uniform base (+ lane*16 by HW)
__device__ __forceinline__ void gl_lds16(const ushort_t* g, ushort_t* lds) {
  __builtin_amdgcn_global_load_lds(
      (const __attribute__((address_space(1))) unsigned int*)(g),
      (__attribute__((address_space(3))) unsigned int*)(lds), 16, 0, 0);
}

// tiled-layout address helpers (panel-local row r in [0,256))
__device__ __forceinline__ size_t tiled_addr(int row, int col) {
  // col in [0,1920)
  return (size_t)(row >> 8) * PANEL_U + (size_t)(col >> 6) * KT_U +
         (size_t)(row & 255) * 64 + (col & 63);
}
__device__ __forceinline__ size_t tiled_addr_tail(int row, int ctail) {
  // ctail in [0,32) = col-1920
  return (size_t)(row >> 8) * PANEL_U + TAIL_U + (size_t)(row & 255) * 32 + ctail;
}

// ---------------- scales: per-column l2-norm partials, then gain*rsqrt ----------------
__global__ void colsum_partial_kernel(const float* __restrict__ wx, const float* __restrict__ wh,
                                      const float* __restrict__ wmx, const float* __restrict__ wmh,
                                      float* __restrict__ parts) {
  int c = blockIdx.x * 256 + threadIdx.x;
  int y = blockIdx.y, p = blockIdx.z;
  const float* W; int K, N; float* out;
  if (y == 0)      { W = wx;  K = 10;   N = FH; out = parts + PW_X  + (size_t)p * FH; }
  else if (y == 1) { W = wh;  K = 1900; N = FH; out = parts + PW_H  + (size_t)p * FH; }
  else if (y == 2) { W = wmx; K = 10;   N = H;  out = parts + PW_MX + (size_t)p * H;  }
  else             { W = wmh; K = 1900; N = H;  out = parts + PW_MH + (size_t)p * H;  }
  if (c >= N) return;
  int rp = (K + 7) / 8;
  int r0 = p * rp, r1 = r0 + rp; if (r1 > K) r1 = K;
  float s = 0.f;
  for (int r = r0; r < r1; ++r) { float v = W[(size_t)r * N + c]; s += v * v; }
  out[c] = s;
}

__global__ void scales_final_kernel(const float* __restrict__ parts,
                                    const float* __restrict__ gx, const float* __restrict__ gh,
                                    const float* __restrict__ gmx, const float* __restrict__ gmh,
                                    float* __restrict__ s_wx, float* __restrict__ s_wh,
                                    float* __restrict__ s_wmx, float* __restrict__ s_wmh) {
  int c = blockIdx.x * 256 + threadIdx.x;
  int y = blockIdx.y;
  const float* pp; int N; const float* g; float* out;
  if (y == 0)      { pp = parts + PW_X;  N = FH; g = gx;  out = s_wx;  }
  else if (y == 1) { pp = parts + PW_H;  N = FH; g = gh;  out = s_wh;  }
  else if (y == 2) { pp = parts + PW_MX; N = H;  g = gmx; out = s_wmx; }
  else             { pp = parts + PW_MH; N = H;  g = gmh; out = s_wmh; }
  if (c >= N) return;
  float s = 0.f;
  for (int p = 0; p < 8; ++p) s += pp[(size_t)p * N + c];
  out[c] = g[c] * rsqrtf(fmaxf(s, 1e-12f));
}

// ---------------- conversions ----------------
__global__ void cvt_h_kernel(const float* __restrict__ h_prev, ushort_t* __restrict__ hbf) {
  size_t idx = (size_t)blockIdx.x * 256 + threadIdx.x;   // < 8192*1952
  int row = (int)(idx / KP), col = (int)(idx % KP);
  float v = (col < H) ? h_prev[(size_t)row * H + col] : 0.f;
  hbf[idx] = f2bf(v);
}

__global__ void wmxn_kernel(const float* __restrict__ wmx, const float* __restrict__ s_wmx,
                            float* __restrict__ wmxn) {
  int idx = blockIdx.x * 256 + threadIdx.x;  // < 19200
  int i = idx / NP_A, j = idx - i * NP_A;
  wmxn[idx] = (j < H) ? wmx[i * H + j] * s_wmx[j] : 0.f;
}

// wmh [1900][1900] -> wmhT [1920][1952] bf16, transposed, pre-scaled (KP layout, gemmA operand)
__global__ void wmhT_kernel(const float* __restrict__ wmh, const float* __restrict__ s_wmh,
                            ushort_t* __restrict__ wmhT) {
  __shared__ float tile[32][33];
  int n0 = blockIdx.x * 32, k0 = blockIdx.y * 32;
  int tx = threadIdx.x & 31, ty = threadIdx.x >> 5;   // ty 0..7
#pragma unroll
  for (int it = 0; it < 4; ++it) {
    int k = k0 + ty + it * 8, n = n0 + tx;
    float v = (k < H && n < H) ? wmh[(size_t)k * H + n] : 0.f;
    tile[ty + it * 8][tx] = v;   // tile[k_local][n_local]
  }
  __syncthreads();
#pragma unroll
  for (int it = 0; it < 4; ++it) {
    int n = n0 + ty + it * 8, k = k0 + tx;
    float v = tile[tx][ty + it * 8];
    float s = (n < H) ? s_wmh[n] : 0.f;
    wmhT[(size_t)n * KP + k] = f2bf(v * s);
  }
}

// wh [1900][7600] + wx [10][7600] -> whxT TILED [30 panels]: row n=4j+g <- col c=g*1900+j,
// k<1900: wh_n ; 1920<=k<1930: wx_n ; else 0. Pre-scaled.
__global__ void whxT_kernel(const float* __restrict__ wh, const float* __restrict__ wx,
                            const float* __restrict__ s_wh, const float* __restrict__ s_wx,
                            ushort_t* __restrict__ whxT) {
  __shared__ float tile[32][33];
  int c0 = blockIdx.x * 32, k0 = blockIdx.y * 32;
  int tx = threadIdx.x & 31, ty = threadIdx.x >> 5;
#pragma unroll
  for (int it = 0; it < 4; ++it) {
    int k = k0 + ty + it * 8, c = c0 + tx;
    float v = 0.f;
    if (c < FH) {
      if (k < H) v = wh[(size_t)k * FH + c] * s_wh[c];
      else if (k >= NP_A && k < NP_A + 10) v = wx[(size_t)(k - NP_A) * FH + c] * s_wx[c];
    }
    tile[ty + it * 8][tx] = v;   // tile[k_local][c_local]
  }
  __syncthreads();
#pragma unroll
  for (int it = 0; it < 4; ++it) {
    int c = c0 + ty + it * 8, k = k0 + tx;
    if (c < FH) {
      int g = c / H; int j = c - g * H; int n = 4 * j + g;
      size_t a = (k < NP_A) ? tiled_addr(n, k) : tiled_addr_tail(n, k - NP_A);
      whxT[a] = f2bf(tile[tx][ty + it * 8]);
    }
  }
}

__global__ void mext_tail_kernel(const float* __restrict__ inputs, ushort_t* __restrict__ m_ext) {
  int idx = blockIdx.x * 256 + threadIdx.x;   // < 8192*32
  int row = idx >> 5, c = idx & 31;
  float v = (c < 10) ? inputs[(size_t)row * 10 + c] : 0.f;
  m_ext[tiled_addr_tail(row, c)] = f2bf(v);
}

__global__ void whxT_tail_kernel(ushort_t* __restrict__ whxT) {
  int idx = blockIdx.x * 256 + threadIdx.x;   // < 80*1952
  int n = 7600 + idx / 1952, k = idx % 1952;
  size_t a = (k < NP_A) ? tiled_addr(n, k) : tiled_addr_tail(n, k - NP_A);
  whxT[a] = 0;
}

// ============ gemmA core: 128x128 tile, BK=32, single-buffer (round-0 proven) ============
__device__ __forceinline__ void gemm_tile128(const ushort_t* __restrict__ Ag,
                                             const ushort_t* __restrict__ Bg,
                                             int m0, int n0,
                                             ushort_t* As, ushort_t* Bs,
                                             f32x4 acc[4][4]) {
  const int tid = threadIdx.x;
  const int lane = tid & 63;
  const int quad = lane >> 4;
  const int lo = lane & 15;
  const int wave = tid >> 6;
  const int wm = (wave & 1) << 6;
  const int wn = (wave >> 1) << 6;
  const int sw = (lo >> 1) & 3;

  const int cr = lane >> 2;
  const int hg = (lane & 3) ^ ((lane >> 3) & 3);
  const int r0 = wave * 16 + cr;
  const int r1 = 64 + wave * 16 + cr;
  const ushort_t* gA0 = Ag + (size_t)(m0 + r0) * KP + hg * 8;
  const ushort_t* gA1 = Ag + (size_t)(m0 + r1) * KP + hg * 8;
  const ushort_t* gB0 = Bg + (size_t)(n0 + r0) * KP + hg * 8;
  const ushort_t* gB1 = Bg + (size_t)(n0 + r1) * KP + hg * 8;
  ushort_t* lA0 = As + (wave * 16) * BK;
  ushort_t* lA1 = As + (64 + wave * 16) * BK;
  ushort_t* lB0 = Bs + (wave * 16) * BK;
  ushort_t* lB1 = Bs + (64 + wave * 16) * BK;

  for (int kt = 0; kt < KITERS; ++kt) {
    __syncthreads();
    gl_lds16(gA0, lA0);
    gl_lds16(gA1, lA1);
    gl_lds16(gB0, lB0);
    gl_lds16(gB1, lB1);
    __syncthreads();
    bf16x8 af[4], bfv[4];
#pragma unroll
    for (int mf = 0; mf < 4; ++mf)
      af[mf] = *(const bf16x8*)(As + (wm + mf * 16 + lo) * BK + ((quad ^ sw) << 3));
#pragma unroll
    for (int nf = 0; nf < 4; ++nf)
      bfv[nf] = *(const bf16x8*)(Bs + (wn + nf * 16 + lo) * BK + ((quad ^ sw) << 3));
#pragma unroll
    for (int mf = 0; mf < 4; ++mf)
#pragma unroll
      for (int nf = 0; nf < 4; ++nf)
        acc[mf][nf] = __builtin_amdgcn_mfma_f32_16x16x32_bf16(af[mf], bfv[nf], acc[mf][nf], 0, 0, 0);
    gA0 += BK; gA1 += BK; gB0 += BK; gB1 += BK;
  }
}

// GEMM-A: P = h_prev_bf @ wmh_n^T ; epilogue m = (inputs·wmx_n) * P -> m_ext (TILED)
__global__ void __launch_bounds__(256) gemmA_kernel(const ushort_t* __restrict__ hbf,
                                                    const ushort_t* __restrict__ wmhT,
                                                    const float* __restrict__ inputs,
                                                    const float* __restrict__ wmxn,
                                                    ushort_t* __restrict__ m_ext) {
  __shared__ __align__(16) char smem[16384];
  ushort_t* As = (ushort_t*)smem;
  ushort_t* Bs = (ushort_t*)(smem + 8192);
  f32x4 acc[4][4];
  f32x4 zv = {0.f, 0.f, 0.f, 0.f};
#pragma unroll
  for (int a = 0; a < 4; ++a)
#pragma unroll
    for (int bq = 0; bq < 4; ++bq) acc[a][bq] = zv;
  int m0 = blockIdx.x * 128, n0 = blockIdx.y * 128;
  gemm_tile128(hbf, wmhT, m0, n0, As, Bs, acc);
  __syncthreads();
  float* inL  = (float*)smem;            // [128][10]
  float* wmxL = (float*)(smem + 5120);   // [10][128]
  for (int t = threadIdx.x; t < 1280; t += 256) {
    int r = t / 10, i = t - r * 10;
    inL[t] = inputs[(size_t)(m0 + r) * 10 + i];
  }
  for (int t = threadIdx.x; t < 1280; t += 256) {
    int i = t >> 7, c = t & 127;
    wmxL[t] = wmxn[i * NP_A + n0 + c];
  }
  __syncthreads();
  const int lane = threadIdx.x & 63, quad = lane >> 4, lo = lane & 15;
  const int wave = threadIdx.x >> 6, wm = (wave & 1) << 6, wn = (wave >> 1) << 6;
#pragma unroll
  for (int mf = 0; mf < 4; ++mf)
#pragma unroll
    for (int r = 0; r < 4; ++r) {
      int rl = wm + mf * 16 + quad * 4 + r;
      float inrow[10];
#pragma unroll
      for (int i = 0; i < 10; ++i) inrow[i] = inL[rl * 10 + i];
#pragma unroll
      for (int nf = 0; nf < 4; ++nf) {
        int cl = wn + nf * 16 + lo;
        float mx = 0.f;
#pragma unroll
        for (int i = 0; i < 10; ++i) mx += inrow[i] * wmxL[i * 128 + cl];
        float mv = acc[mf][nf][r] * mx;
        m_ext[tiled_addr(m0 + rl, n0 + cl)] = f2bf(mv);
      }
    }
}

// ============ gemmB: 256x256 tile, BK=64, 8 waves, 4-phase/K-tile counted-vmcnt ============
// TILED operands: each stage_half reads one contiguous 16KB burst (panel-local).
// LDS swizzle: 16B slot s of row r stored at slot s^(r&7); gl_lds dest linear, source
// pre-swizzled within each 128B row segment (rule #21).
//
// Per K-tile T (buffers cur=T&1): phases P1..P4 as round-2 (hazard-checked; vmcnt(6)
// leaves {B0,A0,B1}(T+2) in flight so tile T+1 is resident at its first read).

__device__ __forceinline__ void stage_half(const ushort_t* __restrict__ Gp, int rbase, int kt,
                                           ushort_t* L, int tid) {
  const int wave = tid >> 6;
#pragma unroll
  for (int q = 0; q < 2; ++q) {
    const int idx = q * 512 + tid;
    const int r = idx >> 3, s = idx & 7;
    const int gs = s ^ (r & 7);
    gl_lds16(Gp + (size_t)kt * KT_U + (size_t)(rbase + r) * 64 + gs * 8,
             L + (size_t)(q * 512 + wave * 64) * 8);
  }
}

__device__ __forceinline__ void read_Ahalf(const ushort_t* A, int wmL, int lo, int mh,
                                           int sw0, int sw1, bf16x8 af[8]) {
#pragma unroll
  for (int mf = 0; mf < 4; ++mf) {
    const ushort_t* p = A + ((wmL + mh * 64 + mf * 16 + lo) << 6);
    af[mf * 2 + 0] = *(const bf16x8*)(p + sw0);
    af[mf * 2 + 1] = *(const bf16x8*)(p + sw1);
  }
}

__device__ __forceinline__ void read_Bhalf(const ushort_t* B, int wnL, int lo, int nh,
                                           int sw0, int sw1, bf16x8 bf[4]) {
#pragma unroll
  for (int nf = 0; nf < 2; ++nf) {
    const ushort_t* p = B + ((wnL + nh * 32 + nf * 16 + lo) << 6);
    bf[nf * 2 + 0] = *(const bf16x8*)(p + sw0);
    bf[nf * 2 + 1] = *(const bf16x8*)(p + sw1);
  }
}

__device__ __forceinline__ void mfma_quad(const bf16x8 af[8], const bf16x8 bf[4],
                                          f32x4 acc[8][4], int mh, int nh) {
#pragma unroll
  for (int mf = 0; mf < 4; ++mf)
#pragma unroll
    for (int nf = 0; nf < 2; ++nf) {
      f32x4 c = acc[mh * 4 + mf][nh * 2 + nf];
      c = __builtin_amdgcn_mfma_f32_16x16x32_bf16(af[mf * 2 + 0], bf[nf * 2 + 0], c, 0, 0, 0);
      c = __builtin_amdgcn_mfma_f32_16x16x32_bf16(af[mf * 2 + 1], bf[nf * 2 + 1], c, 0, 0, 0);
      acc[mh * 4 + mf][nh * 2 + nf] = c;
    }
}

// MODE: 0=steady (stage T+1/T+2, vmcnt(6)), 1=T=NKT-2 (stage only A1(T+1), vmcnt(0)), 2=last
template <int MODE>
__device__ __forceinline__ void b8_iter(const ushort_t* __restrict__ Ap,
                                        const ushort_t* __restrict__ Bp,
                                        int T,
                                        ushort_t* Acur, ushort_t* Bcur,
                                        ushort_t* Anxt, ushort_t* Bnxt,
                                        int tid, int lo, int wmL, int wnL,
                                        int sw0, int sw1, f32x4 acc[8][4]) {
  bf16x8 af[8], b0f[4], b1f[4];
  // P1
  read_Ahalf(Acur, wmL, lo, 0, sw0, sw1, af);
  read_Bhalf(Bcur, wnL, lo, 0, sw0, sw1, b0f);
  if (MODE <= 1) stage_half(Ap, 128, T + 1, Anxt + 8192, tid);
  BAR(); WAIT_LGKM0;
  PRIO1; mfma_quad(af, b0f, acc, 0, 0); PRIO0;
  BAR();
  // P2
  read_Bhalf(Bcur, wnL, lo, 1, sw0, sw1, b1f);
  BAR(); WAIT_LGKM0;
  PRIO1; mfma_quad(af, b1f, acc, 0, 1); PRIO0;
  BAR();
  // P3
  read_Ahalf(Acur, wmL, lo, 1, sw0, sw1, af);
  if (MODE == 0) stage_half(Bp, 0, T + 2, Bcur, tid);
  BAR(); WAIT_LGKM0;
  PRIO1; mfma_quad(af, b1f, acc, 1, 1); PRIO0;
  BAR();
  // P4
  if (MODE == 0) {
    stage_half(Ap, 0, T + 2, Acur, tid);
    stage_half(Bp, 128, T + 2, Bcur + 8192, tid);
    WAIT_VM(6);
  } else if (MODE == 1) {
    WAIT_VM(0);
  }
  BAR();
  PRIO1; mfma_quad(af, b0f, acc, 1, 0); PRIO0;
  BAR();
}

__global__ void __launch_bounds__(512, 2)
gemmB8_kernel(const ushort_t* __restrict__ mext, const ushort_t* __restrict__ whxT,
              const float* __restrict__ bvec, const float* __restrict__ c_prev,
              float* __restrict__ hout, float* __restrict__ cout) {
  extern __shared__ __align__(16) char smem[];
  ushort_t* As0 = (ushort_t*)smem;                 // buf0 A [256][64]
  ushort_t* Bs0 = (ushort_t*)(smem + 32768);       // buf0 B
  ushort_t* As1 = (ushort_t*)(smem + 65536);       // buf1 A
  ushort_t* Bs1 = (ushort_t*)(smem + 98304);       // buf1 B

  const int tid = threadIdx.x;
  const int lane = tid & 63;
  const int lo = lane & 15, quad = lane >> 4;
  const int wave = tid >> 6;
  const int wmL = (wave & 1) << 7;     // 0 / 128
  const int wnL = (wave >> 1) << 6;    // 0 / 64 / 128 / 192
  const int sw0 = ((quad ^ (lo & 7)) << 3);
  const int sw1 = (((4 | quad) ^ (lo & 7)) << 3);

  // XCD panel-ownership mapping: XCD x owns mt in [(x&3)*8, +8), nt in [(x>>2)*15, +15).
  // mt-minor traversal -> 32 concurrent blocks/XCD cover 8mt x 4nt: A shared 4x, B shared 8x.
  int bid = blockIdx.x;
  int xcd = bid & 7, j = bid >> 3;            // j in [0,120)
  int mt = ((xcd & 3) << 3) | (j & 7);        // [0,32)
  int nt = (xcd >> 2) * 15 + (j >> 3);        // [0,30)
  int m0 = mt << 8, n0 = nt << 8;

  f32x4 acc[8][4];
  f32x4 zv = {0.f, 0.f, 0.f, 0.f};
#pragma unroll
  for (int a = 0; a < 8; ++a)
#pragma unroll
    for (int bq = 0; bq < 4; ++bq) acc[a][bq] = zv;

  const ushort_t* Ap = mext + (size_t)mt * PANEL_U;
  const ushort_t* Bp = whxT + (size_t)nt * PANEL_U;

  // prologue: full tile 0 -> buf0, then {B0,A0,B1}(1) -> buf1 (A1(1) issued at P1 of T=0)
  stage_half(Ap, 0,   0, As0,        tid);
  stage_half(Bp, 0,   0, Bs0,        tid);
  stage_half(Ap, 128, 0, As0 + 8192, tid);
  stage_half(Bp, 128, 0, Bs0 + 8192, tid);
  stage_half(Bp, 0,   1, Bs1,        tid);
  stage_half(Ap, 0,   1, As1,        tid);
  stage_half(Bp, 128, 1, Bs1 + 8192, tid);
  WAIT_VM(6);   // tile 0 resident; {B0,A0,B1}(1) in flight
  BAR();

  for (int T = 0; T < NKT - 2; T += 2) {
    b8_iter<0>(Ap, Bp, T,     As0, Bs0, As1, Bs1, tid, lo, wmL, wnL, sw0, sw1, acc);
    b8_iter<0>(Ap, Bp, T + 1, As1, Bs1, As0, Bs0, tid, lo, wmL, wnL, sw0, sw1, acc);
  }
  b8_iter<1>(Ap, Bp, NKT - 2, As0, Bs0, As1, Bs1, tid, lo, wmL, wnL, sw0, sw1, acc);
  b8_iter<2>(Ap, Bp, NKT - 1, As1, Bs1, As0, Bs0, tid, lo, wmL, wnL, sw0, sw1, acc);

  // ---- tail: K columns 1920..1951 (32 wide), staged into buf0 [256][32], swz s^(r&3) ----
  {
    const int wavei = tid >> 6;
#pragma unroll
    for (int q = 0; q < 2; ++q) {
      const int idx = q * 512 + tid;
      const int r = idx >> 2, s = idx & 3;
      const int gs = s ^ (r & 3);
      gl_lds16(Ap + TAIL_U + (size_t)r * 32 + gs * 8,
               As0 + (size_t)(q * 512 + wavei * 64) * 8);
    }
#pragma unroll
    for (int q = 0; q < 2; ++q) {
      const int idx = q * 512 + tid;
      const int r = idx >> 2, s = idx & 3;
      const int gs = s ^ (r & 3);
      gl_lds16(Bp + TAIL_U + (size_t)r * 32 + gs * 8,
               Bs0 + (size_t)(q * 512 + wavei * 64) * 8);
    }
    WAIT_VM(0);
    BAR();
    const int swt = ((quad ^ (lo & 3)) << 3);
    bf16x8 a2[8], b2[4];
#pragma unroll
    for (int mf = 0; mf < 8; ++mf)
      a2[mf] = *(const bf16x8*)(As0 + ((wmL + mf * 16 + lo) << 5) + swt);
#pragma unroll
    for (int nf = 0; nf < 4; ++nf)
      b2[nf] = *(const bf16x8*)(Bs0 + ((wnL + nf * 16 + lo) << 5) + swt);
#pragma unroll
    for (int mf = 0; mf < 8; ++mf)
#pragma unroll
      for (int nf = 0; nf < 4; ++nf)
        acc[mf][nf] = __builtin_amdgcn_mfma_f32_16x16x32_bf16(a2[mf], b2[nf], acc[mf][nf], 0, 0, 0);
  }

  // ---- epilogue: gates via shfl butterfly -> h, c ----
#pragma unroll
  for (int nf = 0; nf < 4; ++nf) {
    int gn = n0 + wnL + nf * 16 + lo;   // permuted col: n = 4j + g
    int j2 = gn >> 2, g = gn & 3;
    float bias = (j2 < H) ? bvec[g * H + j2] : 0.f;
#pragma unroll
    for (int mf = 0; mf < 8; ++mf)
#pragma unroll
      for (int r = 0; r < 4; ++r) {
        float zs = acc[mf][nf][r] + bias;        // gate g
        float v1 = __shfl_xor(zs, 1);            // gate g^1
        float v2 = __shfl_xor(zs, 2);            // gate g^2
        float v3 = __shfl_xor(v1, 2);            // gate g^3
        if (g == r && j2 < H) {
          float zi, zf, zo, zu;
          { int t = 0 ^ g; zi = t == 0 ? zs : t == 1 ? v1 : t == 2 ? v2 : v3; }
          { int t = 1 ^ g; zf = t == 0 ? zs : t == 1 ? v1 : t == 2 ? v2 : v3; }
          { int t = 2 ^ g; zo = t == 0 ? zs : t == 1 ? v1 : t == 2 ? v2 : v3; }
          { int t = 3 ^ g; zu = t == 0 ? zs : t == 1 ? v1 : t == 2 ? v2 : v3; }
          float iv = 1.f / (1.f + __expf(-zi));
          float fv = 1.f / (1.f + __expf(-zf));
          float ov = 1.f / (1.f + __expf(-zo));
          float uv = tanhf(zu);
          int row = m0 + wmL + mf * 16 + quad * 4 + r;
          size_t oidx = (size_t)row * H + j2;
          float cp = c_prev[oidx];
          float cv = fv * cp + iv * uv;
          hout[oidx] = ov * tanhf(cv);
          cout[oidx] = cv;
        }
      }
  }
}

extern "C" void kernel_launch(void* const* d_in, const int* in_sizes, int n_in,
                              void* d_out, int out_size, void* d_ws, size_t ws_size,
                              hipStream_t stream) {
  const float* inputs = (const float*)d_in[0];
  const float* c_prev = (const float*)d_in[1];
  const float* h_prev = (const float*)d_in[2];
  const float* wx  = (const float*)d_in[3];
  const float* wh  = (const float*)d_in[4];
  const float* wmx = (const float*)d_in[5];
  const float* wmh = (const float*)d_in[6];
  const float* bv  = (const float*)d_in[7];
  const float* gx  = (const float*)d_in[8];
  const float* gh  = (const float*)d_in[9];
  const float* gmx = (const float*)d_in[10];
  const float* gmh = (const float*)d_in[11];

  char* ws = (char*)d_ws;
  float* s_wx  = (float*)(ws + OFF_SWX);
  float* s_wh  = (float*)(ws + OFF_SWH);
  float* s_wmx = (float*)(ws + OFF_SWMX);
  float* s_wmh = (float*)(ws + OFF_SWMH);
  float* wmxn  = (float*)(ws + OFF_WMXN);
  float* parts = (float*)(ws + OFF_PART);
  ushort_t* hbf   = (ushort_t*)(ws + OFF_HBF);
  ushort_t* m_ext = (ushort_t*)(ws + OFF_MEXT);
  ushort_t* wmhT  = (ushort_t*)(ws + OFF_WMHT);
  ushort_t* whxT  = (ushort_t*)(ws + OFF_WHXT);

  float* hout = (float*)d_out;
  float* cout = hout + (size_t)BATCH * H;

  static bool attr_set = false;
  if (!attr_set) {
    hipFuncSetAttribute(reinterpret_cast<const void*>(&gemmB8_kernel),
                        hipFuncAttributeMaxDynamicSharedMemorySize, 131072);
    attr_set = true;
  }

  colsum_partial_kernel<<<dim3(30, 4, 8), 256, 0, stream>>>(wx, wh, wmx, wmh, parts);
  scales_final_kernel<<<dim3(30, 4), 256, 0, stream>>>(parts, gx, gh, gmx, gmh,
                                                       s_wx, s_wh, s_wmx, s_wmh);
  cvt_h_kernel<<<62464, 256, 0, stream>>>(h_prev, hbf);
  wmxn_kernel<<<75, 256, 0, stream>>>(wmx, s_wmx, wmxn);
  wmhT_kernel<<<dim3(60, 61), 256, 0, stream>>>(wmh, s_wmh, wmhT);
  whxT_kernel<<<dim3(238, 61), 256, 0, stream>>>(wh, wx, s_wh, s_wx, whxT);
  mext_tail_kernel<<<1024, 256, 0, stream>>>(inputs, m_ext);
  whxT_tail_kernel<<<610, 256, 0, stream>>>(whxT);
  gemmA_kernel<<<dim3(64, 15), 256, 0, stream>>>(hbf, wmhT, inputs, wmxn, m_ext);
  gemmB8_kernel<<<dim3(960), 512, 131072, stream>>>(m_ext, whxT, bv, c_prev, hout, cout);
}